// Round 6
// baseline (584.363 us; speedup 1.0000x reference)
//
#include <hip/hip_runtime.h>
#include <hip/hip_bf16.h>

#define NN 100000
#define NE 625000
#define HH 128
#define DOUT 64
#define NHTOT (NN * HH)          // 12,800,000 feature elements
#define SCAN_B 391               // ceil(NN/256)
#define WTOT 107712              // canonical weight element count

// canonical weight offsets (elements)
#define OW_Wl  0
#define OW_bl  49152
#define OW_Wr  49536
#define OW_gam 98688
#define OW_bet 99072
#define OW_Wo  99456
#define OW_bo  107648

typedef unsigned int u32;
typedef unsigned short u16;
typedef long long i64;
typedef short bf16x8 __attribute__((ext_vector_type(8)));   // 8 bf16 = 4 VGPR
typedef float f32x4 __attribute__((ext_vector_type(4)));

__device__ __forceinline__ float bflo(u32 v) { return __uint_as_float(v << 16); }
__device__ __forceinline__ float bfhi(u32 v) { return __uint_as_float(v & 0xffff0000u); }
__device__ __forceinline__ float bf2f(u16 u) { return __uint_as_float(((u32)u) << 16); }
__device__ __forceinline__ u16 f2b(float f) {
    __hip_bfloat16 h = __float2bfloat16(f);   // RNE
    return *(u16*)&h;
}
__device__ __forceinline__ int edge_at(const void* ei, int is64, i64 idx) {
    return is64 ? (int)((const i64*)ei)[idx] : ((const int*)ei)[idx];
}

// ---- dtype sniffer: flags[0]=1 if x is fp32, flags[1]=1 if edge_index is int64 ----
__global__ void k_sniff(const u16* __restrict__ x, const int* __restrict__ ei,
                        int* __restrict__ flags) {
    __shared__ int cbad, cnz;
    int t = threadIdx.x;
    if (t == 0) { cbad = 0; cnz = 0; }
    __syncthreads();
    u16 u = x[t];
    int e = (u >> 7) & 0xff;            // bf16 exponent field
    if (e >= 132) atomicAdd(&cbad, 1);
    if (t < 32) { if (ei[2 * t + 1] != 0) atomicAdd(&cnz, 1); }
    __syncthreads();
    if (t == 0) {
        flags[0] = (cbad > 4) ? 1 : 0;  // fp32 floats
        flags[1] = (cnz == 0) ? 1 : 0;  // int64 edges
    }
}

// ---- canonicalize x -> bf16 buffer ----
__global__ void k_cvt(const void* __restrict__ xin, uint2* __restrict__ out,
                      const int* __restrict__ flags) {
    int gid = blockIdx.x * 256 + threadIdx.x;   // grid = NHTOT/4/256 exact
    if (flags[0]) {
        float4 v = ((const float4*)xin)[gid];
        uint2 r;
        r.x = (u32)f2b(v.x) | ((u32)f2b(v.y) << 16);
        r.y = (u32)f2b(v.z) | ((u32)f2b(v.w) << 16);
        out[gid] = r;
    } else {
        out[gid] = ((const uint2*)xin)[gid];
    }
}

// ---- canonicalize all weights/biases -> bf16 ----
__global__ void k_cvtw(const void* Wl, const void* bl, const void* Wr,
                       const void* gam, const void* bet, const void* Wo,
                       const void* bo, u16* __restrict__ wc,
                       const int* __restrict__ flags) {
    int gid = blockIdx.x * 256 + threadIdx.x;
    if (gid >= WTOT) return;
    const void* p; int li;
    if      (gid < OW_bl)  { p = Wl;  li = gid; }
    else if (gid < OW_Wr)  { p = bl;  li = gid - OW_bl; }
    else if (gid < OW_gam) { p = Wr;  li = gid - OW_Wr; }
    else if (gid < OW_bet) { p = gam; li = gid - OW_gam; }
    else if (gid < OW_Wo)  { p = bet; li = gid - OW_bet; }
    else if (gid < OW_bo)  { p = Wo;  li = gid - OW_Wo; }
    else                   { p = bo;  li = gid - OW_bo; }
    wc[gid] = flags[0] ? f2b(((const float*)p)[li]) : ((const u16*)p)[li];
}

// ---- degree histogram over dst ----
__global__ void k_hist(const void* __restrict__ ei, int* __restrict__ cnt,
                       const int* __restrict__ flags) {
    int e = blockIdx.x * 256 + threadIdx.x;
    if (e < NE) {
        int d = edge_at(ei, flags[1], (i64)NE + e);
        if ((unsigned)d < NN) atomicAdd(&cnt[d], 1);
    }
}

// ---- scan step 1: per-block sums ----
__global__ void k_scan1(const int* __restrict__ cnt, int* __restrict__ part) {
    __shared__ int sh[256];
    int t = threadIdx.x, g = blockIdx.x * 256 + t;
    sh[t] = (g < NN) ? cnt[g] : 0;
    __syncthreads();
    for (int s = 128; s > 0; s >>= 1) { if (t < s) sh[t] += sh[t + s]; __syncthreads(); }
    if (t == 0) part[blockIdx.x] = sh[0];
}

// ---- scan step 2: exclusive scan of SCAN_B partials ----
__global__ void k_scan2(int* part) {
    __shared__ int sh[512];
    int t = threadIdx.x;
    int v = (t < SCAN_B) ? part[t] : 0;
    sh[t] = v; __syncthreads();
    for (int off = 1; off < 512; off <<= 1) {
        int a = (t >= off) ? sh[t - off] : 0;
        __syncthreads(); sh[t] += a; __syncthreads();
    }
    if (t < SCAN_B) part[t] = sh[t] - v;   // exclusive
}

// ---- scan step 3: offsets, cursor, invdeg ----
__global__ void k_scan3(const int* __restrict__ cnt, const int* __restrict__ part,
                        int* __restrict__ offs, int* __restrict__ cur,
                        float* __restrict__ invdeg) {
    __shared__ int sh[256];
    int t = threadIdx.x, g = blockIdx.x * 256 + t;
    int c = (g < NN) ? cnt[g] : 0;
    sh[t] = c; __syncthreads();
    for (int off = 1; off < 256; off <<= 1) {
        int a = (t >= off) ? sh[t - off] : 0;
        __syncthreads(); sh[t] += a; __syncthreads();
    }
    if (g < NN) {
        int start = part[blockIdx.x] + sh[t] - c;
        offs[g] = start; cur[g] = start;
        invdeg[g] = 1.0f / fmaxf((float)c, 1.0f);
        if (g == NN - 1) offs[NN] = start + c;
    }
}

// ---- counting-sort src by dst ----
__global__ void k_sort(const void* __restrict__ ei, int* __restrict__ cur,
                       int* __restrict__ ssrc, const int* __restrict__ flags) {
    int e = blockIdx.x * 256 + threadIdx.x;
    if (e < NE) {
        int is64 = flags[1];
        int d = edge_at(ei, is64, (i64)NE + e);
        int s = edge_at(ei, is64, (i64)e);
        if ((unsigned)d < NN) {
            int p = atomicAdd(&cur[d], 1);
            if ((unsigned)p < NE) ssrc[p] = s;
        }
    }
}

// ---- FUSED: scatter-mean aggregation + dual-GEMM + bias + residual + LN + ReLU ----
// Block = 256 thr / 4 waves / 128 nodes. AGG never touches global memory:
// each wave gathers its 32 nodes' neighbor rows and writes bf16 means into a
// 32 KB LDS tile (chunk-XOR swizzle). W is staged in 32 KB halves (Wl phase,
// then Wr restaged into the same buffer). Total LDS 64 KB -> 2 blocks/CU.
// MFMA mapping identical to round 4/5 (verified): A: m=lane&15 node,
// k=kt*32+quad*8+j; B from W rows; C/D: row(node)=quad*4+r, col(feat)=lane&15.
__global__ __launch_bounds__(256, 2) void k_fused(
        const u16* __restrict__ X, u16* __restrict__ OUT,
        const u16* __restrict__ Wl, const u16* __restrict__ Wr,
        const u16* __restrict__ bl, const u16* __restrict__ gam,
        const u16* __restrict__ bet,
        const int* __restrict__ offs, const int* __restrict__ ssrc,
        const float* __restrict__ invdeg, int residual) {
    __shared__ __align__(16) u32 AS[8192];    // 32 KB: agg tile [128 nodes][16 chunks, XOR-swizzled]
    __shared__ __align__(16) u16 WS[16384];   // 32 KB: one W matrix [ft][kt][quad][mn] 16B chunks
    int tid = threadIdx.x;
    int wave = tid >> 6, lane = tid & 63;
    int mn = lane & 15, quad = lane >> 4;
    int n0w = blockIdx.x * 128 + wave * 32;

    // ---- issue Wl stage loads (complete while we prefetch CSR meta) ----
    bf16x8 wreg[8];
    #pragma unroll
    for (int it = 0; it < 8; ++it) {
        int cid = it * 256 + tid;   // == (ft*4+kt)*64 + q*16 + f16
        int ft = cid >> 8, kt = (cid >> 6) & 3, q = (cid >> 4) & 3, f16 = cid & 15;
        wreg[it] = *(const bf16x8*)(Wl + (size_t)(ft * 16 + f16) * HH + kt * 32 + q * 8);
    }
    // CSR meta prefetch: lane j<32 holds node n0w+j's extent
    int o0 = 0, o1 = 0; float ivv = 0.f;
    {
        int gn = n0w + lane;
        if (lane < 32 && gn < NN) { o0 = offs[gn]; o1 = offs[gn + 1]; ivv = invdeg[gn]; }
    }
    #pragma unroll
    for (int it = 0; it < 8; ++it)
        *(bf16x8*)&WS[(size_t)(it * 256 + tid) * 8] = wreg[it];

    // ---- gather/mean: one node at a time, whole wave reads the 256B row ----
    for (int j = 0; j < 32; ++j) {
        int s0 = __shfl(o0, j), s1 = __shfl(o1, j);
        float a0 = 0.f, a1 = 0.f;
        for (int base = s0; base < s1; base += 64) {
            int cnt = min(64, s1 - base);
            int idx = ssrc[base + min(lane, cnt - 1)];
            idx = min(max(idx, 0), NN - 1);
            int jj = 0;
            for (; jj + 4 <= cnt; jj += 4) {
                int i0 = __shfl(idx, jj),     i1 = __shfl(idx, jj + 1);
                int i2 = __shfl(idx, jj + 2), i3 = __shfl(idx, jj + 3);
                u32 v0 = ((const u32*)X)[(size_t)i0 * 64 + lane];
                u32 v1 = ((const u32*)X)[(size_t)i1 * 64 + lane];
                u32 v2 = ((const u32*)X)[(size_t)i2 * 64 + lane];
                u32 v3 = ((const u32*)X)[(size_t)i3 * 64 + lane];
                a0 += bflo(v0) + bflo(v1) + bflo(v2) + bflo(v3);
                a1 += bfhi(v0) + bfhi(v1) + bfhi(v2) + bfhi(v3);
            }
            for (; jj < cnt; ++jj) {
                u32 v = ((const u32*)X)[(size_t)__shfl(idx, jj) * 64 + lane];
                a0 += bflo(v); a1 += bfhi(v);
            }
        }
        float iv = __shfl(ivv, j);
        u32 r = (u32)f2b(a0 * iv) | ((u32)f2b(a1 * iv) << 16);
        // node (wave*32+j), word lane: chunk (lane>>2) XOR-swizzled by j&15
        AS[(wave * 32 + j) * 64 + (((lane >> 2) ^ (j & 15)) << 2) + (lane & 3)] = r;
    }

    // ---- X A-fragments straight from global ----
    bf16x8 afrX[2][4];
    #pragma unroll
    for (int g = 0; g < 2; ++g) {
        int ngc = min(n0w + g * 16 + mn, NN - 1);
        const u16* xr = X + (size_t)ngc * HH;
        #pragma unroll
        for (int kt = 0; kt < 4; ++kt)
            afrX[g][kt] = *(const bf16x8*)(xr + kt * 32 + quad * 8);
    }

    __syncthreads();

    // ---- AGG A-fragments from LDS ----
    bf16x8 afrA[2][4];
    #pragma unroll
    for (int g = 0; g < 2; ++g) {
        int ln = wave * 32 + g * 16 + mn;
        #pragma unroll
        for (int kt = 0; kt < 4; ++kt)
            afrA[g][kt] = *(const bf16x8*)&AS[ln * 64 + (((kt * 4 + quad) ^ mn) << 2)];
    }

    f32x4 acc[8][2];
    #pragma unroll
    for (int ft = 0; ft < 8; ++ft)
        #pragma unroll
        for (int g = 0; g < 2; ++g) acc[ft][g] = (f32x4){0.f, 0.f, 0.f, 0.f};

    // issue Wr loads now; they complete during the Wl-half MFMAs
    #pragma unroll
    for (int it = 0; it < 8; ++it) {
        int cid = it * 256 + tid;
        int ft = cid >> 8, kt = (cid >> 6) & 3, q = (cid >> 4) & 3, f16 = cid & 15;
        wreg[it] = *(const bf16x8*)(Wr + (size_t)(ft * 16 + f16) * HH + kt * 32 + q * 8);
    }

    int laneoff = (quad * 16 + mn) * 8;
    #pragma unroll
    for (int ft = 0; ft < 8; ++ft) {
        #pragma unroll
        for (int kt = 0; kt < 4; ++kt) {
            bf16x8 b = *(const bf16x8*)&WS[(ft * 4 + kt) * 512 + laneoff];
            acc[ft][0] = __builtin_amdgcn_mfma_f32_16x16x32_bf16(afrA[0][kt], b, acc[ft][0], 0, 0, 0);
            acc[ft][1] = __builtin_amdgcn_mfma_f32_16x16x32_bf16(afrA[1][kt], b, acc[ft][1], 0, 0, 0);
        }
    }

    __syncthreads();   // all waves done reading Wl half
    #pragma unroll
    for (int it = 0; it < 8; ++it)
        *(bf16x8*)&WS[(size_t)(it * 256 + tid) * 8] = wreg[it];
    __syncthreads();   // Wr staged

    #pragma unroll
    for (int ft = 0; ft < 8; ++ft) {
        #pragma unroll
        for (int kt = 0; kt < 4; ++kt) {
            bf16x8 b = *(const bf16x8*)&WS[(ft * 4 + kt) * 512 + laneoff];
            acc[ft][0] = __builtin_amdgcn_mfma_f32_16x16x32_bf16(afrX[0][kt], b, acc[ft][0], 0, 0, 0);
            acc[ft][1] = __builtin_amdgcn_mfma_f32_16x16x32_bf16(afrX[1][kt], b, acc[ft][1], 0, 0, 0);
        }
    }

    // ---- epilogue per node group: bias + residual + LN + relu ----
    #pragma unroll
    for (int g = 0; g < 2; ++g) {
        int nb = n0w + g * 16;
        float s1[4] = {0, 0, 0, 0}, s2[4] = {0, 0, 0, 0};
        #pragma unroll
        for (int ft = 0; ft < 8; ++ft) {
            int f = ft * 16 + mn;
            float bv = bf2f(bl[f]);
            #pragma unroll
            for (int r = 0; r < 4; ++r) {
                int ndc = min(nb + quad * 4 + r, NN - 1);
                float res = residual ? bf2f(X[(size_t)ndc * HH + f]) : 0.f;
                float v = acc[ft][g][r] + bv + res;
                acc[ft][g][r] = v;
                s1[r] += v; s2[r] += v * v;
            }
        }
        #pragma unroll
        for (int msk = 1; msk < 16; msk <<= 1) {
            #pragma unroll
            for (int r = 0; r < 4; ++r) {
                s1[r] += __shfl_xor(s1[r], msk, 64);
                s2[r] += __shfl_xor(s2[r], msk, 64);
            }
        }
        #pragma unroll
        for (int r = 0; r < 4; ++r) {
            float mu = s1[r] * (1.0f / 128.0f);
            float var = s2[r] * (1.0f / 128.0f) - mu * mu;
            float rs = rsqrtf(fmaxf(var, 0.f) + 1e-5f);
            s1[r] = mu; s2[r] = rs;
        }
        #pragma unroll
        for (int ft = 0; ft < 8; ++ft) {
            int f = ft * 16 + mn;
            float gm = bf2f(gam[f]), bt = bf2f(bet[f]);
            #pragma unroll
            for (int r = 0; r < 4; ++r) {
                int nd = nb + quad * 4 + r;
                if (nd < NN) {
                    float v = (acc[ft][g][r] - s1[r]) * s2[r] * gm + bt;
                    OUT[(size_t)nd * HH + f] = f2b(fmaxf(v, 0.f));
                }
            }
        }
    }
}

// ---- MFMA final projection: out = x3 @ Wo^T + bo ----
__global__ __launch_bounds__(256) void k_proj(
        const u16* __restrict__ Xf, const u16* __restrict__ Wo,
        const u16* __restrict__ bo, void* __restrict__ out,
        const int* __restrict__ flags) {
    int tid = threadIdx.x;
    int wave = tid >> 6, lane = tid & 63;
    int mn = lane & 15, quad = lane >> 4;
    int n0 = (blockIdx.x * 4 + wave) * 16;
    if (n0 >= NN) return;

    int ngc = min(n0 + mn, NN - 1);
    const u16* xrow = Xf + (size_t)ngc * HH;
    bf16x8 afr[4];
    #pragma unroll
    for (int kt = 0; kt < 4; ++kt)
        afr[kt] = *(const bf16x8*)(xrow + kt * 32 + quad * 8);

    f32x4 acc[4];
    #pragma unroll
    for (int ft = 0; ft < 4; ++ft) acc[ft] = (f32x4){0.f, 0.f, 0.f, 0.f};
    #pragma unroll
    for (int ft = 0; ft < 4; ++ft) {
        const u16* worow = Wo + (size_t)(ft * 16 + mn) * HH;
        #pragma unroll
        for (int kt = 0; kt < 4; ++kt) {
            bf16x8 b = *(const bf16x8*)(worow + kt * 32 + quad * 8);
            acc[ft] = __builtin_amdgcn_mfma_f32_16x16x32_bf16(afr[kt], b, acc[ft], 0, 0, 0);
        }
    }
    int isf32 = flags[0];
    #pragma unroll
    for (int ft = 0; ft < 4; ++ft) {
        int f = ft * 16 + mn;
        float bv = bf2f(bo[f]);
        #pragma unroll
        for (int r = 0; r < 4; ++r) {
            int nd = n0 + quad * 4 + r;
            if (nd < NN) {
                float v = acc[ft][r] + bv;
                if (isf32) ((float*)out)[(size_t)nd * DOUT + f] = v;
                else       ((u16*)out)[(size_t)nd * DOUT + f]   = f2b(v);
            }
        }
    }
}

extern "C" void kernel_launch(void* const* d_in, const int* in_sizes, int n_in,
                              void* d_out, int out_size, void* d_ws, size_t ws_size,
                              hipStream_t stream) {
    const void* xin = d_in[0];
    const void* ei  = d_in[1];     // [2][NE]: row0=src, row1=dst

    u16*   xc     = (u16*)d_ws;                 // NHTOT bf16
    u16*   b0     = xc + NHTOT;                 // NHTOT bf16
    u16*   wc     = b0 + NHTOT;                 // WTOT (padded to 107776)
    float* invdeg = (float*)(wc + 107776);      // NN
    int*   cnt    = (int*)(invdeg + NN);        // NN
    int*   cur    = cnt + NN;                   // NN
    int*   offs   = cur + NN;                   // NN+1
    int*   ssrc   = offs + NN + 1;              // NE
    int*   part   = ssrc + NE;                  // 512
    int*   flags  = part + 512;                 // 2

    k_sniff<<<1, 256, 0, stream>>>((const u16*)xin, (const int*)ei, flags);
    hipMemsetAsync(cnt, 0, NN * sizeof(int), stream);
    hipMemsetAsync(ssrc, 0, NE * sizeof(int), stream);
    k_cvt <<<NHTOT / 4 / 256, 256, 0, stream>>>(xin, (uint2*)xc, flags);
    k_cvtw<<<(WTOT + 255) / 256, 256, 0, stream>>>(d_in[2], d_in[3], d_in[4],
            d_in[5], d_in[6], d_in[7], d_in[8], wc, flags);
    k_hist<<<(NE + 255) / 256, 256, 0, stream>>>(ei, cnt, flags);
    k_scan1<<<SCAN_B, 256, 0, stream>>>(cnt, part);
    k_scan2<<<1, 512, 0, stream>>>(part);
    k_scan3<<<SCAN_B, 256, 0, stream>>>(cnt, part, offs, cur, invdeg);
    k_sort<<<(NE + 255) / 256, 256, 0, stream>>>(ei, cur, ssrc, flags);

    const u16* Wl  = wc + OW_Wl;
    const u16* bl  = wc + OW_bl;
    const u16* Wr  = wc + OW_Wr;
    const u16* gam = wc + OW_gam;
    const u16* bet = wc + OW_bet;
    const u16* Wo  = wc + OW_Wo;
    const u16* bo  = wc + OW_bo;

    int gblk = (NN + 127) / 128;   // 128 nodes per block
    // layer 0: xc -> b0
    k_fused<<<gblk, 256, 0, stream>>>(xc, b0, Wl, Wr, bl, gam, bet,
                                      offs, ssrc, invdeg, 0);
    // layer 1: b0 -> xc
    k_fused<<<gblk, 256, 0, stream>>>(b0, xc,
            Wl + HH * HH, Wr + HH * HH, bl + HH, gam + HH, bet + HH,
            offs, ssrc, invdeg, 1);
    // layer 2: xc -> b0
    k_fused<<<gblk, 256, 0, stream>>>(xc, b0,
            Wl + 2 * HH * HH, Wr + 2 * HH * HH, bl + 2 * HH, gam + 2 * HH, bet + 2 * HH,
            offs, ssrc, invdeg, 1);

    k_proj<<<(NN + 63) / 64, 256, 0, stream>>>(b0, Wo, bo, d_out, flags);
}

// Round 7
// 361.005 us; speedup vs baseline: 1.6187x; 1.6187x over previous
//
#include <hip/hip_runtime.h>
#include <hip/hip_bf16.h>

#define NN 100000
#define NE 625000
#define HH 128
#define DOUT 64
#define NHTOT (NN * HH)          // 12,800,000 feature elements
#define SCAN_B 391               // ceil(NN/256)
#define WTOT 107712              // canonical weight element count

// canonical weight offsets (elements)
#define OW_Wl  0
#define OW_bl  49152
#define OW_Wr  49536
#define OW_gam 98688
#define OW_bet 99072
#define OW_Wo  99456
#define OW_bo  107648

typedef unsigned int u32;
typedef unsigned short u16;
typedef long long i64;
typedef short bf16x8 __attribute__((ext_vector_type(8)));   // 8 bf16 = 4 VGPR
typedef float f32x4 __attribute__((ext_vector_type(4)));

__device__ __forceinline__ float bflo(u32 v) { return __uint_as_float(v << 16); }
__device__ __forceinline__ float bfhi(u32 v) { return __uint_as_float(v & 0xffff0000u); }
__device__ __forceinline__ float bf2f(u16 u) { return __uint_as_float(((u32)u) << 16); }
__device__ __forceinline__ u16 f2b(float f) {
    __hip_bfloat16 h = __float2bfloat16(f);   // RNE
    return *(u16*)&h;
}
__device__ __forceinline__ int edge_at(const void* ei, int is64, i64 idx) {
    return is64 ? (int)((const i64*)ei)[idx] : ((const int*)ei)[idx];
}

// ---- dtype sniffer: flags[0]=1 if x is fp32, flags[1]=1 if edge_index is int64 ----
__global__ void k_sniff(const u16* __restrict__ x, const int* __restrict__ ei,
                        int* __restrict__ flags) {
    __shared__ int cbad, cnz;
    int t = threadIdx.x;
    if (t == 0) { cbad = 0; cnz = 0; }
    __syncthreads();
    u16 u = x[t];
    int e = (u >> 7) & 0xff;            // bf16 exponent field
    if (e >= 132) atomicAdd(&cbad, 1);
    if (t < 32) { if (ei[2 * t + 1] != 0) atomicAdd(&cnz, 1); }
    __syncthreads();
    if (t == 0) {
        flags[0] = (cbad > 4) ? 1 : 0;  // fp32 floats
        flags[1] = (cnz == 0) ? 1 : 0;  // int64 edges
    }
}

// ---- canonicalize x -> bf16 buffer ----
__global__ void k_cvt(const void* __restrict__ xin, uint2* __restrict__ out,
                      const int* __restrict__ flags) {
    int gid = blockIdx.x * 256 + threadIdx.x;   // grid = NHTOT/4/256 exact
    if (flags[0]) {
        float4 v = ((const float4*)xin)[gid];
        uint2 r;
        r.x = (u32)f2b(v.x) | ((u32)f2b(v.y) << 16);
        r.y = (u32)f2b(v.z) | ((u32)f2b(v.w) << 16);
        out[gid] = r;
    } else {
        out[gid] = ((const uint2*)xin)[gid];
    }
}

// ---- canonicalize weights -> bf16; folds +I into Wr for residual layers ----
__global__ void k_cvtw(const void* Wl, const void* bl, const void* Wr,
                       const void* gam, const void* bet, const void* Wo,
                       const void* bo, u16* __restrict__ wc,
                       const int* __restrict__ flags) {
    int gid = blockIdx.x * 256 + threadIdx.x;
    if (gid >= WTOT) return;
    const void* p; int li; float add = 0.f;
    if      (gid < OW_bl)  { p = Wl;  li = gid; }
    else if (gid < OW_Wr)  { p = bl;  li = gid - OW_bl; }
    else if (gid < OW_gam) { p = Wr;  li = gid - OW_Wr;
                             int lay = li >> 14, rc = li & 16383;
                             if (lay > 0 && (rc >> 7) == (rc & 127)) add = 1.0f; }
    else if (gid < OW_bet) { p = gam; li = gid - OW_gam; }
    else if (gid < OW_Wo)  { p = bet; li = gid - OW_bet; }
    else if (gid < OW_bo)  { p = Wo;  li = gid - OW_Wo; }
    else                   { p = bo;  li = gid - OW_bo; }
    float v = flags[0] ? ((const float*)p)[li] : bf2f(((const u16*)p)[li]);
    wc[gid] = f2b(v + add);
}

// ---- degree histogram over dst ----
__global__ void k_hist(const void* __restrict__ ei, int* __restrict__ cnt,
                       const int* __restrict__ flags) {
    int e = blockIdx.x * 256 + threadIdx.x;
    if (e < NE) {
        int d = edge_at(ei, flags[1], (i64)NE + e);
        if ((unsigned)d < NN) atomicAdd(&cnt[d], 1);
    }
}

// ---- scan step 1: per-block sums ----
__global__ void k_scan1(const int* __restrict__ cnt, int* __restrict__ part) {
    __shared__ int sh[256];
    int t = threadIdx.x, g = blockIdx.x * 256 + t;
    sh[t] = (g < NN) ? cnt[g] : 0;
    __syncthreads();
    for (int s = 128; s > 0; s >>= 1) { if (t < s) sh[t] += sh[t + s]; __syncthreads(); }
    if (t == 0) part[blockIdx.x] = sh[0];
}

// ---- scan step 2: exclusive scan of SCAN_B partials ----
__global__ void k_scan2(int* part) {
    __shared__ int sh[512];
    int t = threadIdx.x;
    int v = (t < SCAN_B) ? part[t] : 0;
    sh[t] = v; __syncthreads();
    for (int off = 1; off < 512; off <<= 1) {
        int a = (t >= off) ? sh[t - off] : 0;
        __syncthreads(); sh[t] += a; __syncthreads();
    }
    if (t < SCAN_B) part[t] = sh[t] - v;   // exclusive
}

// ---- scan step 3: offsets, cursor, invdeg ----
__global__ void k_scan3(const int* __restrict__ cnt, const int* __restrict__ part,
                        int* __restrict__ offs, int* __restrict__ cur,
                        float* __restrict__ invdeg) {
    __shared__ int sh[256];
    int t = threadIdx.x, g = blockIdx.x * 256 + t;
    int c = (g < NN) ? cnt[g] : 0;
    sh[t] = c; __syncthreads();
    for (int off = 1; off < 256; off <<= 1) {
        int a = (t >= off) ? sh[t - off] : 0;
        __syncthreads(); sh[t] += a; __syncthreads();
    }
    if (g < NN) {
        int start = part[blockIdx.x] + sh[t] - c;
        offs[g] = start; cur[g] = start;
        invdeg[g] = 1.0f / fmaxf((float)c, 1.0f);
        if (g == NN - 1) offs[NN] = start + c;
    }
}

// ---- counting-sort src by dst ----
__global__ void k_sort(const void* __restrict__ ei, int* __restrict__ cur,
                       int* __restrict__ ssrc, const int* __restrict__ flags) {
    int e = blockIdx.x * 256 + threadIdx.x;
    if (e < NE) {
        int is64 = flags[1];
        int d = edge_at(ei, is64, (i64)NE + e);
        int s = edge_at(ei, is64, (i64)e);
        if ((unsigned)d < NN) {
            int p = atomicAdd(&cur[d], 1);
            if ((unsigned)p < NE) ssrc[p] = s;
        }
    }
}

// ---- aggregation: two nodes per wave (one per 32-lane half), uint2 rows ----
__global__ void k_agg(const uint2* __restrict__ X2, const int* __restrict__ offs,
                      const int* __restrict__ ssrc, const float* __restrict__ invdeg,
                      uint2* __restrict__ AGG2) {
    int wid = (blockIdx.x * 256 + threadIdx.x) >> 6;
    int lane = threadIdx.x & 63;
    int half = lane >> 5, sl = lane & 31;
    int node = wid * 2 + half;           // grid sized so node < NN exactly
    int s0 = offs[node], s1 = offs[node + 1];
    float a0 = 0.f, a1 = 0.f, a2 = 0.f, a3 = 0.f;
    for (int base = s0; base < s1; base += 32) {
        int cnt = min(32, s1 - base);
        int idx = ssrc[base + min(sl, cnt - 1)];   // coalesced index prefetch
        idx = min(max(idx, 0), NN - 1);
        int j = 0;
        for (; j + 4 <= cnt; j += 4) {
            int i0 = __shfl(idx, j, 32),     i1 = __shfl(idx, j + 1, 32);
            int i2 = __shfl(idx, j + 2, 32), i3 = __shfl(idx, j + 3, 32);
            uint2 v0 = X2[(size_t)i0 * 32 + sl];
            uint2 v1 = X2[(size_t)i1 * 32 + sl];
            uint2 v2 = X2[(size_t)i2 * 32 + sl];
            uint2 v3 = X2[(size_t)i3 * 32 + sl];
            a0 += bflo(v0.x) + bflo(v1.x) + bflo(v2.x) + bflo(v3.x);
            a1 += bfhi(v0.x) + bfhi(v1.x) + bfhi(v2.x) + bfhi(v3.x);
            a2 += bflo(v0.y) + bflo(v1.y) + bflo(v2.y) + bflo(v3.y);
            a3 += bfhi(v0.y) + bfhi(v1.y) + bfhi(v2.y) + bfhi(v3.y);
        }
        for (; j < cnt; ++j) {
            uint2 v = X2[(size_t)__shfl(idx, j, 32) * 32 + sl];
            a0 += bflo(v.x); a1 += bfhi(v.x);
            a2 += bflo(v.y); a3 += bfhi(v.y);
        }
    }
    float iv = invdeg[node];
    uint2 r;
    r.x = (u32)f2b(a0 * iv) | ((u32)f2b(a1 * iv) << 16);
    r.y = (u32)f2b(a2 * iv) | ((u32)f2b(a3 * iv) << 16);
    AGG2[(size_t)node * 32 + sl] = r;
}

// ---- MFMA fused dual-GEMM + bias + LayerNorm + ReLU (residual folded into Wr) ----
// Block = 256 thr / 4 waves / 128 nodes. All global reads coalesced:
// A tiles (AGG then X) staged through 32 KB swizzled LDS; W staged in 32 KB
// halves (Wl then Wr). Total LDS 64 KB -> 2 blocks/CU.
// A-frag: m=lane&15 node, k=kt*32+quad*8+j. C/D: row=quad*4+r, col=lane&15.
__global__ __launch_bounds__(256, 2) void k_gemm(
        const u16* __restrict__ X, u16* __restrict__ AGG,
        const u16* __restrict__ Wl, const u16* __restrict__ Wr,
        const u16* __restrict__ bl, const u16* __restrict__ gam,
        const u16* __restrict__ bet) {
    __shared__ __align__(16) u16 WS[16384];   // 32 KB: one W matrix in frag order
    __shared__ __align__(16) u32 AS[8192];    // 32 KB: 128-node tile, chunk-XOR swizzle
    int tid = threadIdx.x;
    int wave = tid >> 6, lane = tid & 63;
    int mn = lane & 15, quad = lane >> 4;
    int n0 = blockIdx.x * 128;
    int n0w = n0 + wave * 32;

    // issue Wl + AGG-tile loads (each thread: 8 chunks of each, coalesced)
    bf16x8 wreg[8], areg[8];
    #pragma unroll
    for (int it = 0; it < 8; ++it) {
        int cid = it * 256 + tid;             // 0..2047
        int ft = cid >> 8, kt = (cid >> 6) & 3, q = (cid >> 4) & 3, f16 = cid & 15;
        wreg[it] = *(const bf16x8*)(Wl + (size_t)(ft * 16 + f16) * HH + kt * 32 + q * 8);
        int n = cid >> 4, c = cid & 15;
        int ng = min(n0 + n, NN - 1);
        areg[it] = *(const bf16x8*)(AGG + (size_t)ng * HH + c * 8);
    }
    #pragma unroll
    for (int it = 0; it < 8; ++it) {
        int cid = it * 256 + tid;
        int n = cid >> 4, c = cid & 15;
        *(bf16x8*)&WS[(size_t)cid * 8] = wreg[it];
        *(bf16x8*)&AS[(size_t)(n * 16 + (c ^ (n & 15))) * 4] = areg[it];
    }
    __syncthreads();

    // AGG A-frags from LDS; meanwhile issue Wr + X-tile loads
    bf16x8 afr[2][4];
    #pragma unroll
    for (int g = 0; g < 2; ++g) {
        int ln = wave * 32 + g * 16 + mn;
        #pragma unroll
        for (int kt = 0; kt < 4; ++kt)
            afr[g][kt] = *(const bf16x8*)&AS[(size_t)(ln * 16 + ((kt * 4 + quad) ^ mn)) * 4];
    }
    #pragma unroll
    for (int it = 0; it < 8; ++it) {
        int cid = it * 256 + tid;
        int ft = cid >> 8, kt = (cid >> 6) & 3, q = (cid >> 4) & 3, f16 = cid & 15;
        wreg[it] = *(const bf16x8*)(Wr + (size_t)(ft * 16 + f16) * HH + kt * 32 + q * 8);
        int n = cid >> 4, c = cid & 15;
        int ng = min(n0 + n, NN - 1);
        areg[it] = *(const bf16x8*)(X + (size_t)ng * HH + c * 8);
    }

    f32x4 acc[8][2];
    #pragma unroll
    for (int ft = 0; ft < 8; ++ft)
        #pragma unroll
        for (int g = 0; g < 2; ++g) acc[ft][g] = (f32x4){0.f, 0.f, 0.f, 0.f};

    int laneoff = (quad * 16 + mn) * 8;
    // phase 1: AGG @ Wl^T
    #pragma unroll
    for (int ft = 0; ft < 8; ++ft) {
        #pragma unroll
        for (int kt = 0; kt < 4; ++kt) {
            bf16x8 b = *(const bf16x8*)&WS[(ft * 4 + kt) * 512 + laneoff];
            acc[ft][0] = __builtin_amdgcn_mfma_f32_16x16x32_bf16(afr[0][kt], b, acc[ft][0], 0, 0, 0);
            acc[ft][1] = __builtin_amdgcn_mfma_f32_16x16x32_bf16(afr[1][kt], b, acc[ft][1], 0, 0, 0);
        }
    }

    __syncthreads();   // everyone done with Wl / AGG tile
    #pragma unroll
    for (int it = 0; it < 8; ++it) {
        int cid = it * 256 + tid;
        int n = cid >> 4, c = cid & 15;
        *(bf16x8*)&WS[(size_t)cid * 8] = wreg[it];
        *(bf16x8*)&AS[(size_t)(n * 16 + (c ^ (n & 15))) * 4] = areg[it];
    }
    __syncthreads();   // Wr + X tile staged

    #pragma unroll
    for (int g = 0; g < 2; ++g) {
        int ln = wave * 32 + g * 16 + mn;
        #pragma unroll
        for (int kt = 0; kt < 4; ++kt)
            afr[g][kt] = *(const bf16x8*)&AS[(size_t)(ln * 16 + ((kt * 4 + quad) ^ mn)) * 4];
    }
    // phase 2: X @ (Wr + I)^T   (residual folded)
    #pragma unroll
    for (int ft = 0; ft < 8; ++ft) {
        #pragma unroll
        for (int kt = 0; kt < 4; ++kt) {
            bf16x8 b = *(const bf16x8*)&WS[(ft * 4 + kt) * 512 + laneoff];
            acc[ft][0] = __builtin_amdgcn_mfma_f32_16x16x32_bf16(afr[0][kt], b, acc[ft][0], 0, 0, 0);
            acc[ft][1] = __builtin_amdgcn_mfma_f32_16x16x32_bf16(afr[1][kt], b, acc[ft][1], 0, 0, 0);
        }
    }

    // epilogue per node group: bias + LN + relu
    #pragma unroll
    for (int g = 0; g < 2; ++g) {
        int nb = n0w + g * 16;
        float s1[4] = {0, 0, 0, 0}, s2[4] = {0, 0, 0, 0};
        #pragma unroll
        for (int ft = 0; ft < 8; ++ft) {
            int f = ft * 16 + mn;
            float bv = bf2f(bl[f]);
            #pragma unroll
            for (int r = 0; r < 4; ++r) {
                float v = acc[ft][g][r] + bv;
                acc[ft][g][r] = v;
                s1[r] += v; s2[r] += v * v;
            }
        }
        #pragma unroll
        for (int msk = 1; msk < 16; msk <<= 1) {
            #pragma unroll
            for (int r = 0; r < 4; ++r) {
                s1[r] += __shfl_xor(s1[r], msk, 64);
                s2[r] += __shfl_xor(s2[r], msk, 64);
            }
        }
        #pragma unroll
        for (int r = 0; r < 4; ++r) {
            float mu = s1[r] * (1.0f / 128.0f);
            float var = s2[r] * (1.0f / 128.0f) - mu * mu;
            float rs = rsqrtf(fmaxf(var, 0.f) + 1e-5f);
            s1[r] = mu; s2[r] = rs;
        }
        #pragma unroll
        for (int ft = 0; ft < 8; ++ft) {
            int f = ft * 16 + mn;
            float gm = bf2f(gam[f]), bt = bf2f(bet[f]);
            #pragma unroll
            for (int r = 0; r < 4; ++r) {
                int nd = nb + quad * 4 + r;
                if (nd < NN) {
                    float v = (acc[ft][g][r] - s1[r]) * s2[r] * gm + bt;
                    AGG[(size_t)nd * HH + f] = f2b(fmaxf(v, 0.f));
                }
            }
        }
    }
}

// ---- MFMA final projection: out = x3 @ Wo^T + bo; Wo + X tile staged in LDS ----
__global__ __launch_bounds__(256) void k_proj(
        const u16* __restrict__ Xf, const u16* __restrict__ Wo,
        const u16* __restrict__ bo, void* __restrict__ out,
        const int* __restrict__ flags) {
    __shared__ __align__(16) u16 WoS[8192];   // 16 KB
    __shared__ __align__(16) u32 AS[4096];    // 16 KB: 64-node tile
    int tid = threadIdx.x;
    int wave = tid >> 6, lane = tid & 63;
    int mn = lane & 15, quad = lane >> 4;
    int n0 = blockIdx.x * 64;

    bf16x8 wreg[4], areg[4];
    #pragma unroll
    for (int it = 0; it < 4; ++it) {
        int cid = it * 256 + tid;             // 0..1023
        int ft = cid >> 8, kt = (cid >> 6) & 3, q = (cid >> 4) & 3, f16 = cid & 15;
        wreg[it] = *(const bf16x8*)(Wo + (size_t)(ft * 16 + f16) * HH + kt * 32 + q * 8);
        int n = cid >> 4, c = cid & 15;
        int ng = min(n0 + n, NN - 1);
        areg[it] = *(const bf16x8*)(Xf + (size_t)ng * HH + c * 8);
    }
    #pragma unroll
    for (int it = 0; it < 4; ++it) {
        int cid = it * 256 + tid;
        int n = cid >> 4, c = cid & 15;
        *(bf16x8*)&WoS[(size_t)cid * 8] = wreg[it];
        *(bf16x8*)&AS[(size_t)(n * 16 + (c ^ (n & 15))) * 4] = areg[it];
    }
    __syncthreads();

    bf16x8 afr[4];
    int ln = wave * 16 + mn;
    #pragma unroll
    for (int kt = 0; kt < 4; ++kt)
        afr[kt] = *(const bf16x8*)&AS[(size_t)(ln * 16 + ((kt * 4 + quad) ^ mn)) * 4];

    f32x4 acc[4];
    #pragma unroll
    for (int ft = 0; ft < 4; ++ft) acc[ft] = (f32x4){0.f, 0.f, 0.f, 0.f};
    int laneoff = (quad * 16 + mn) * 8;
    #pragma unroll
    for (int ft = 0; ft < 4; ++ft) {
        #pragma unroll
        for (int kt = 0; kt < 4; ++kt) {
            bf16x8 b = *(const bf16x8*)&WoS[(ft * 4 + kt) * 512 + laneoff];
            acc[ft] = __builtin_amdgcn_mfma_f32_16x16x32_bf16(afr[kt], b, acc[ft], 0, 0, 0);
        }
    }
    int isf32 = flags[0];
    int nbase = n0 + wave * 16;
    #pragma unroll
    for (int ft = 0; ft < 4; ++ft) {
        int f = ft * 16 + mn;
        float bv = bf2f(bo[f]);
        #pragma unroll
        for (int r = 0; r < 4; ++r) {
            int nd = nbase + quad * 4 + r;
            if (nd < NN) {
                float v = acc[ft][r] + bv;
                if (isf32) ((float*)out)[(size_t)nd * DOUT + f] = v;
                else       ((u16*)out)[(size_t)nd * DOUT + f]   = f2b(v);
            }
        }
    }
}

extern "C" void kernel_launch(void* const* d_in, const int* in_sizes, int n_in,
                              void* d_out, int out_size, void* d_ws, size_t ws_size,
                              hipStream_t stream) {
    const void* xin = d_in[0];
    const void* ei  = d_in[1];     // [2][NE]: row0=src, row1=dst

    u16*   xc     = (u16*)d_ws;                 // NHTOT bf16
    u16*   b0     = xc + NHTOT;                 // NHTOT bf16
    u16*   wc     = b0 + NHTOT;                 // WTOT (padded to 107776)
    float* invdeg = (float*)(wc + 107776);      // NN
    int*   cnt    = (int*)(invdeg + NN);        // NN
    int*   cur    = cnt + NN;                   // NN
    int*   offs   = cur + NN;                   // NN+1
    int*   ssrc   = offs + NN + 1;              // NE
    int*   part   = ssrc + NE;                  // 512
    int*   flags  = part + 512;                 // 2

    k_sniff<<<1, 256, 0, stream>>>((const u16*)xin, (const int*)ei, flags);
    hipMemsetAsync(cnt, 0, NN * sizeof(int), stream);
    k_cvt <<<NHTOT / 4 / 256, 256, 0, stream>>>(xin, (uint2*)xc, flags);
    k_cvtw<<<(WTOT + 255) / 256, 256, 0, stream>>>(d_in[2], d_in[3], d_in[4],
            d_in[5], d_in[6], d_in[7], d_in[8], wc, flags);
    k_hist<<<(NE + 255) / 256, 256, 0, stream>>>(ei, cnt, flags);
    k_scan1<<<SCAN_B, 256, 0, stream>>>(cnt, part);
    k_scan2<<<1, 512, 0, stream>>>(part);
    k_scan3<<<SCAN_B, 256, 0, stream>>>(cnt, part, offs, cur, invdeg);
    k_sort<<<(NE + 255) / 256, 256, 0, stream>>>(ei, cur, ssrc, flags);

    const u16* Wl  = wc + OW_Wl;
    const u16* bl  = wc + OW_bl;
    const u16* Wr  = wc + OW_Wr;
    const u16* gam = wc + OW_gam;
    const u16* bet = wc + OW_bet;
    const u16* Wo  = wc + OW_Wo;
    const u16* bo  = wc + OW_bo;

    int ablk = NN / 8;               // 2 nodes/wave * 4 waves = 8 nodes/block, exact
    int gblk = (NN + 127) / 128;     // 128 nodes per block
    // layer 0: X=xc, agg->b0, gemm in place over b0
    k_agg<<<ablk, 256, 0, stream>>>((const uint2*)xc, offs, ssrc, invdeg, (uint2*)b0);
    k_gemm<<<gblk, 256, 0, stream>>>(xc, b0, Wl, Wr, bl, gam, bet);
    // layer 1: X=b0, agg->xc, gemm in place over xc (Wr has +I folded)
    k_agg<<<ablk, 256, 0, stream>>>((const uint2*)b0, offs, ssrc, invdeg, (uint2*)xc);
    k_gemm<<<gblk, 256, 0, stream>>>(b0, xc,
            Wl + HH * HH, Wr + HH * HH, bl + HH, gam + HH, bet + HH);
    // layer 2: X=xc, agg->b0, gemm in place over b0 (Wr has +I folded)
    k_agg<<<ablk, 256, 0, stream>>>((const uint2*)xc, offs, ssrc, invdeg, (uint2*)b0);
    k_gemm<<<gblk, 256, 0, stream>>>(xc, b0,
            Wl + 2 * HH * HH, Wr + 2 * HH * HH, bl + 2 * HH, gam + 2 * HH, bet + 2 * HH);

    k_proj<<<(NN + 63) / 64, 256, 0, stream>>>(b0, Wo, bo, d_out, flags);
}

// Round 8
// 346.579 us; speedup vs baseline: 1.6861x; 1.0416x over previous
//
#include <hip/hip_runtime.h>
#include <hip/hip_bf16.h>

#define NN 100000
#define NE 625000
#define HH 128
#define DOUT 64
#define NHTOT (NN * HH)          // 12,800,000 feature elements
#define SCAN_B 391               // ceil(NN/256)
#define WTOT 107712              // canonical weight element count

// canonical weight offsets (elements)
#define OW_Wl  0
#define OW_bl  49152
#define OW_Wr  49536
#define OW_gam 98688
#define OW_bet 99072
#define OW_Wo  99456
#define OW_bo  107648

typedef unsigned int u32;
typedef unsigned short u16;
typedef long long i64;
typedef short bf16x8 __attribute__((ext_vector_type(8)));   // 8 bf16 = 4 VGPR
typedef float f32x4 __attribute__((ext_vector_type(4)));

__device__ __forceinline__ float bflo(u32 v) { return __uint_as_float(v << 16); }
__device__ __forceinline__ float bfhi(u32 v) { return __uint_as_float(v & 0xffff0000u); }
__device__ __forceinline__ float bf2f(u16 u) { return __uint_as_float(((u32)u) << 16); }
__device__ __forceinline__ u16 f2b(float f) {
    __hip_bfloat16 h = __float2bfloat16(f);   // RNE
    return *(u16*)&h;
}
__device__ __forceinline__ int edge_at(const void* ei, int is64, i64 idx) {
    return is64 ? (int)((const i64*)ei)[idx] : ((const int*)ei)[idx];
}

// ---- dtype sniffer: flags[0]=1 if x is fp32, flags[1]=1 if edge_index is int64 ----
__global__ void k_sniff(const u16* __restrict__ x, const int* __restrict__ ei,
                        int* __restrict__ flags) {
    __shared__ int cbad, cnz;
    int t = threadIdx.x;
    if (t == 0) { cbad = 0; cnz = 0; }
    __syncthreads();
    u16 u = x[t];
    int e = (u >> 7) & 0xff;            // bf16 exponent field
    if (e >= 132) atomicAdd(&cbad, 1);
    if (t < 32) { if (ei[2 * t + 1] != 0) atomicAdd(&cnz, 1); }
    __syncthreads();
    if (t == 0) {
        flags[0] = (cbad > 4) ? 1 : 0;  // fp32 floats
        flags[1] = (cnz == 0) ? 1 : 0;  // int64 edges
    }
}

// ---- canonicalize x -> bf16 buffer ----
__global__ void k_cvt(const void* __restrict__ xin, uint2* __restrict__ out,
                      const int* __restrict__ flags) {
    int gid = blockIdx.x * 256 + threadIdx.x;   // grid = NHTOT/4/256 exact
    if (flags[0]) {
        float4 v = ((const float4*)xin)[gid];
        uint2 r;
        r.x = (u32)f2b(v.x) | ((u32)f2b(v.y) << 16);
        r.y = (u32)f2b(v.z) | ((u32)f2b(v.w) << 16);
        out[gid] = r;
    } else {
        out[gid] = ((const uint2*)xin)[gid];
    }
}

// ---- canonicalize weights -> bf16; folds +I into Wr for residual layers ----
__global__ void k_cvtw(const void* Wl, const void* bl, const void* Wr,
                       const void* gam, const void* bet, const void* Wo,
                       const void* bo, u16* __restrict__ wc,
                       const int* __restrict__ flags) {
    int gid = blockIdx.x * 256 + threadIdx.x;
    if (gid >= WTOT) return;
    const void* p; int li; float add = 0.f;
    if      (gid < OW_bl)  { p = Wl;  li = gid; }
    else if (gid < OW_Wr)  { p = bl;  li = gid - OW_bl; }
    else if (gid < OW_gam) { p = Wr;  li = gid - OW_Wr;
                             int lay = li >> 14, rc = li & 16383;
                             if (lay > 0 && (rc >> 7) == (rc & 127)) add = 1.0f; }
    else if (gid < OW_bet) { p = gam; li = gid - OW_gam; }
    else if (gid < OW_Wo)  { p = bet; li = gid - OW_bet; }
    else if (gid < OW_bo)  { p = Wo;  li = gid - OW_Wo; }
    else                   { p = bo;  li = gid - OW_bo; }
    float v = flags[0] ? ((const float*)p)[li] : bf2f(((const u16*)p)[li]);
    wc[gid] = f2b(v + add);
}

// ---- degree histogram over dst ----
__global__ void k_hist(const void* __restrict__ ei, int* __restrict__ cnt,
                       const int* __restrict__ flags) {
    int e = blockIdx.x * 256 + threadIdx.x;
    if (e < NE) {
        int d = edge_at(ei, flags[1], (i64)NE + e);
        if ((unsigned)d < NN) atomicAdd(&cnt[d], 1);
    }
}

// ---- scan step 1: per-block sums ----
__global__ void k_scan1(const int* __restrict__ cnt, int* __restrict__ part) {
    __shared__ int sh[256];
    int t = threadIdx.x, g = blockIdx.x * 256 + t;
    sh[t] = (g < NN) ? cnt[g] : 0;
    __syncthreads();
    for (int s = 128; s > 0; s >>= 1) { if (t < s) sh[t] += sh[t + s]; __syncthreads(); }
    if (t == 0) part[blockIdx.x] = sh[0];
}

// ---- scan step 2: exclusive scan of SCAN_B partials ----
__global__ void k_scan2(int* part) {
    __shared__ int sh[512];
    int t = threadIdx.x;
    int v = (t < SCAN_B) ? part[t] : 0;
    sh[t] = v; __syncthreads();
    for (int off = 1; off < 512; off <<= 1) {
        int a = (t >= off) ? sh[t - off] : 0;
        __syncthreads(); sh[t] += a; __syncthreads();
    }
    if (t < SCAN_B) part[t] = sh[t] - v;   // exclusive
}

// ---- scan step 3: offsets, cursor, invdeg ----
__global__ void k_scan3(const int* __restrict__ cnt, const int* __restrict__ part,
                        int* __restrict__ offs, int* __restrict__ cur,
                        float* __restrict__ invdeg) {
    __shared__ int sh[256];
    int t = threadIdx.x, g = blockIdx.x * 256 + t;
    int c = (g < NN) ? cnt[g] : 0;
    sh[t] = c; __syncthreads();
    for (int off = 1; off < 256; off <<= 1) {
        int a = (t >= off) ? sh[t - off] : 0;
        __syncthreads(); sh[t] += a; __syncthreads();
    }
    if (g < NN) {
        int start = part[blockIdx.x] + sh[t] - c;
        offs[g] = start; cur[g] = start;
        invdeg[g] = 1.0f / fmaxf((float)c, 1.0f);
        if (g == NN - 1) offs[NN] = start + c;
    }
}

// ---- counting-sort src by dst ----
__global__ void k_sort(const void* __restrict__ ei, int* __restrict__ cur,
                       int* __restrict__ ssrc, const int* __restrict__ flags) {
    int e = blockIdx.x * 256 + threadIdx.x;
    if (e < NE) {
        int is64 = flags[1];
        int d = edge_at(ei, is64, (i64)NE + e);
        int s = edge_at(ei, is64, (i64)e);
        if ((unsigned)d < NN) {
            int p = atomicAdd(&cur[d], 1);
            if ((unsigned)p < NE) ssrc[p] = s;
        }
    }
}

// ---- aggregation: 4 nodes/wave (16-lane groups), bf16x8 loads, unroll 4 ----
// 16 lanes x 16B = 256B row; 16 outstanding rows/wave.
__global__ void k_agg(const bf16x8* __restrict__ Xv, const int* __restrict__ offs,
                      const int* __restrict__ ssrc, const float* __restrict__ invdeg,
                      bf16x8* __restrict__ AGGv) {
    int node = (blockIdx.x * 256 + threadIdx.x) >> 4;   // grid exact: NN*16/256
    int gl = threadIdx.x & 15;
    int s0 = offs[node], s1 = offs[node + 1];
    float a[8];
    #pragma unroll
    for (int e = 0; e < 8; ++e) a[e] = 0.f;
    for (int base = s0; base < s1; base += 16) {
        int cnt = min(16, s1 - base);
        int idx = ssrc[base + min(gl, cnt - 1)];   // coalesced index prefetch
        idx = min(max(idx, 0), NN - 1);
        int j = 0;
        for (; j + 4 <= cnt; j += 4) {
            int i0 = __shfl(idx, j, 16),     i1 = __shfl(idx, j + 1, 16);
            int i2 = __shfl(idx, j + 2, 16), i3 = __shfl(idx, j + 3, 16);
            bf16x8 v0 = Xv[(size_t)i0 * 16 + gl];
            bf16x8 v1 = Xv[(size_t)i1 * 16 + gl];
            bf16x8 v2 = Xv[(size_t)i2 * 16 + gl];
            bf16x8 v3 = Xv[(size_t)i3 * 16 + gl];
            #pragma unroll
            for (int e = 0; e < 8; ++e)
                a[e] += bf2f((u16)v0[e]) + bf2f((u16)v1[e])
                      + bf2f((u16)v2[e]) + bf2f((u16)v3[e]);
        }
        for (; j < cnt; ++j) {
            bf16x8 v = Xv[(size_t)__shfl(idx, j, 16) * 16 + gl];
            #pragma unroll
            for (int e = 0; e < 8; ++e) a[e] += bf2f((u16)v[e]);
        }
    }
    float iv = invdeg[node];
    bf16x8 r;
    #pragma unroll
    for (int e = 0; e < 8; ++e) r[e] = (short)f2b(a[e] * iv);
    AGGv[(size_t)node * 16 + gl] = r;
}

// ---- MFMA fused dual-GEMM + bias + LN + ReLU (+optional fused projection) ----
// Block = 256 thr / 4 waves / 128 nodes. A tiles staged via 32 KB swizzled
// LDS; W staged in 32 KB halves. FUSE=1: h3 round-trips through the A-LDS
// (C-layout -> A-layout), Wo restaged into WS, out written directly.
template <int FUSE>
__global__ __launch_bounds__(256, 2) void k_gemm(
        const u16* __restrict__ X, u16* __restrict__ AGG,
        const u16* __restrict__ Wl, const u16* __restrict__ Wr,
        const u16* __restrict__ bl, const u16* __restrict__ gam,
        const u16* __restrict__ bet,
        const u16* __restrict__ Wo, const u16* __restrict__ bo,
        void* __restrict__ out, const int* __restrict__ flags) {
    __shared__ __align__(16) u16 WS[16384];   // 32 KB: one W matrix in frag order
    __shared__ __align__(16) u32 AS[8192];    // 32 KB: 128-node tile, chunk-XOR swizzle
    int tid = threadIdx.x;
    int wave = tid >> 6, lane = tid & 63;
    int mn = lane & 15, quad = lane >> 4;
    int n0 = blockIdx.x * 128;
    int n0w = n0 + wave * 32;

    // issue Wl + AGG-tile loads (each thread: 8 chunks of each, coalesced)
    bf16x8 wreg[8], areg[8];
    #pragma unroll
    for (int it = 0; it < 8; ++it) {
        int cid = it * 256 + tid;             // 0..2047
        int ft = cid >> 8, kt = (cid >> 6) & 3, q = (cid >> 4) & 3, f16 = cid & 15;
        wreg[it] = *(const bf16x8*)(Wl + (size_t)(ft * 16 + f16) * HH + kt * 32 + q * 8);
        int n = cid >> 4, c = cid & 15;
        int ng = min(n0 + n, NN - 1);
        areg[it] = *(const bf16x8*)(AGG + (size_t)ng * HH + c * 8);
    }
    #pragma unroll
    for (int it = 0; it < 8; ++it) {
        int cid = it * 256 + tid;
        int n = cid >> 4, c = cid & 15;
        *(bf16x8*)&WS[(size_t)cid * 8] = wreg[it];
        *(bf16x8*)&AS[(size_t)(n * 16 + (c ^ (n & 15))) * 4] = areg[it];
    }
    __syncthreads();

    // AGG A-frags from LDS; meanwhile issue Wr + X-tile loads
    bf16x8 afr[2][4];
    #pragma unroll
    for (int g = 0; g < 2; ++g) {
        int ln = wave * 32 + g * 16 + mn;
        #pragma unroll
        for (int kt = 0; kt < 4; ++kt)
            afr[g][kt] = *(const bf16x8*)&AS[(size_t)(ln * 16 + ((kt * 4 + quad) ^ mn)) * 4];
    }
    #pragma unroll
    for (int it = 0; it < 8; ++it) {
        int cid = it * 256 + tid;
        int ft = cid >> 8, kt = (cid >> 6) & 3, q = (cid >> 4) & 3, f16 = cid & 15;
        wreg[it] = *(const bf16x8*)(Wr + (size_t)(ft * 16 + f16) * HH + kt * 32 + q * 8);
        int n = cid >> 4, c = cid & 15;
        int ng = min(n0 + n, NN - 1);
        areg[it] = *(const bf16x8*)(X + (size_t)ng * HH + c * 8);
    }

    f32x4 acc[8][2];
    #pragma unroll
    for (int ft = 0; ft < 8; ++ft)
        #pragma unroll
        for (int g = 0; g < 2; ++g) acc[ft][g] = (f32x4){0.f, 0.f, 0.f, 0.f};

    int laneoff = (quad * 16 + mn) * 8;
    // phase 1: AGG @ Wl^T
    #pragma unroll
    for (int ft = 0; ft < 8; ++ft) {
        #pragma unroll
        for (int kt = 0; kt < 4; ++kt) {
            bf16x8 b = *(const bf16x8*)&WS[(ft * 4 + kt) * 512 + laneoff];
            acc[ft][0] = __builtin_amdgcn_mfma_f32_16x16x32_bf16(afr[0][kt], b, acc[ft][0], 0, 0, 0);
            acc[ft][1] = __builtin_amdgcn_mfma_f32_16x16x32_bf16(afr[1][kt], b, acc[ft][1], 0, 0, 0);
        }
    }

    __syncthreads();   // everyone done with Wl / AGG tile
    #pragma unroll
    for (int it = 0; it < 8; ++it) {
        int cid = it * 256 + tid;
        int n = cid >> 4, c = cid & 15;
        *(bf16x8*)&WS[(size_t)cid * 8] = wreg[it];
        *(bf16x8*)&AS[(size_t)(n * 16 + (c ^ (n & 15))) * 4] = areg[it];
    }
    __syncthreads();   // Wr + X tile staged

    #pragma unroll
    for (int g = 0; g < 2; ++g) {
        int ln = wave * 32 + g * 16 + mn;
        #pragma unroll
        for (int kt = 0; kt < 4; ++kt)
            afr[g][kt] = *(const bf16x8*)&AS[(size_t)(ln * 16 + ((kt * 4 + quad) ^ mn)) * 4];
    }
    // phase 2: X @ (Wr + I)^T   (residual folded)
    #pragma unroll
    for (int ft = 0; ft < 8; ++ft) {
        #pragma unroll
        for (int kt = 0; kt < 4; ++kt) {
            bf16x8 b = *(const bf16x8*)&WS[(ft * 4 + kt) * 512 + laneoff];
            acc[ft][0] = __builtin_amdgcn_mfma_f32_16x16x32_bf16(afr[0][kt], b, acc[ft][0], 0, 0, 0);
            acc[ft][1] = __builtin_amdgcn_mfma_f32_16x16x32_bf16(afr[1][kt], b, acc[ft][1], 0, 0, 0);
        }
    }

    if (FUSE) __syncthreads();   // AS free for h3 (all phase-2 frag reads done)

    // epilogue per node group: bias + LN + relu
    u16* AS2 = (u16*)AS;   // FUSE: h3 tile [128 nodes][128 feats], chunk-XOR swizzle
    #pragma unroll
    for (int g = 0; g < 2; ++g) {
        int nb = n0w + g * 16;
        float s1[4] = {0, 0, 0, 0}, s2[4] = {0, 0, 0, 0};
        #pragma unroll
        for (int ft = 0; ft < 8; ++ft) {
            int f = ft * 16 + mn;
            float bv = bf2f(bl[f]);
            #pragma unroll
            for (int r = 0; r < 4; ++r) {
                float v = acc[ft][g][r] + bv;
                acc[ft][g][r] = v;
                s1[r] += v; s2[r] += v * v;
            }
        }
        #pragma unroll
        for (int msk = 1; msk < 16; msk <<= 1) {
            #pragma unroll
            for (int r = 0; r < 4; ++r) {
                s1[r] += __shfl_xor(s1[r], msk, 64);
                s2[r] += __shfl_xor(s2[r], msk, 64);
            }
        }
        #pragma unroll
        for (int r = 0; r < 4; ++r) {
            float mu = s1[r] * (1.0f / 128.0f);
            float var = s2[r] * (1.0f / 128.0f) - mu * mu;
            float rs = rsqrtf(fmaxf(var, 0.f) + 1e-5f);
            s1[r] = mu; s2[r] = rs;
        }
        #pragma unroll
        for (int ft = 0; ft < 8; ++ft) {
            int f = ft * 16 + mn;
            float gm = bf2f(gam[f]), bt = bf2f(bet[f]);
            #pragma unroll
            for (int r = 0; r < 4; ++r) {
                float v = (acc[ft][g][r] - s1[r]) * s2[r] * gm + bt;
                u16 hb = f2b(fmaxf(v, 0.f));
                if (FUSE) {
                    int ln = wave * 32 + g * 16 + quad * 4 + r;   // local node
                    AS2[ln * 128 + (((f >> 3) ^ (ln & 15)) << 3) + (f & 7)] = hb;
                } else {
                    int nd = nb + quad * 4 + r;
                    if (nd < NN) AGG[(size_t)nd * HH + f] = hb;
                }
            }
        }
    }

    if (FUSE) {
        // stage Wo (64x128 -> 1024 chunks) into WS; WS reads all done
        bf16x8 wo[4];
        #pragma unroll
        for (int it = 0; it < 4; ++it) {
            int cid = it * 256 + tid;         // 0..1023
            int ft = cid >> 8, kt = (cid >> 6) & 3, q = (cid >> 4) & 3, f16 = cid & 15;
            wo[it] = *(const bf16x8*)(Wo + (size_t)(ft * 16 + f16) * HH + kt * 32 + q * 8);
        }
        #pragma unroll
        for (int it = 0; it < 4; ++it)
            *(bf16x8*)&WS[(size_t)(it * 256 + tid) * 8] = wo[it];
        __syncthreads();   // h3 + Wo staged

        bf16x8 pfr[2][4];
        #pragma unroll
        for (int g = 0; g < 2; ++g) {
            int ln = wave * 32 + g * 16 + mn;
            #pragma unroll
            for (int kt = 0; kt < 4; ++kt)
                pfr[g][kt] = *(const bf16x8*)&AS2[ln * 128 + (((kt * 4 + quad) ^ (ln & 15)) << 3)];
        }
        f32x4 pacc[4][2];
        #pragma unroll
        for (int ft = 0; ft < 4; ++ft)
            #pragma unroll
            for (int g = 0; g < 2; ++g) pacc[ft][g] = (f32x4){0.f, 0.f, 0.f, 0.f};
        #pragma unroll
        for (int ft = 0; ft < 4; ++ft) {
            #pragma unroll
            for (int kt = 0; kt < 4; ++kt) {
                bf16x8 b = *(const bf16x8*)&WS[(ft * 4 + kt) * 512 + laneoff];
                pacc[ft][0] = __builtin_amdgcn_mfma_f32_16x16x32_bf16(pfr[0][kt], b, pacc[ft][0], 0, 0, 0);
                pacc[ft][1] = __builtin_amdgcn_mfma_f32_16x16x32_bf16(pfr[1][kt], b, pacc[ft][1], 0, 0, 0);
            }
        }
        int isf32 = flags[0];
        #pragma unroll
        for (int g = 0; g < 2; ++g) {
            #pragma unroll
            for (int ft = 0; ft < 4; ++ft) {
                int f = ft * 16 + mn;
                float bv = bf2f(bo[f]);
                #pragma unroll
                for (int r = 0; r < 4; ++r) {
                    int nd = n0w + g * 16 + quad * 4 + r;
                    if (nd < NN) {
                        float v = pacc[ft][g][r] + bv;
                        if (isf32) ((float*)out)[(size_t)nd * DOUT + f] = v;
                        else       ((u16*)out)[(size_t)nd * DOUT + f]   = f2b(v);
                    }
                }
            }
        }
    }
}

extern "C" void kernel_launch(void* const* d_in, const int* in_sizes, int n_in,
                              void* d_out, int out_size, void* d_ws, size_t ws_size,
                              hipStream_t stream) {
    const void* xin = d_in[0];
    const void* ei  = d_in[1];     // [2][NE]: row0=src, row1=dst

    u16*   xc     = (u16*)d_ws;                 // NHTOT bf16
    u16*   b0     = xc + NHTOT;                 // NHTOT bf16
    u16*   wc     = b0 + NHTOT;                 // WTOT (padded to 107776)
    float* invdeg = (float*)(wc + 107776);      // NN
    int*   cnt    = (int*)(invdeg + NN);        // NN
    int*   cur    = cnt + NN;                   // NN
    int*   offs   = cur + NN;                   // NN+1
    int*   ssrc   = offs + NN + 1;              // NE
    int*   part   = ssrc + NE;                  // 512
    int*   flags  = part + 512;                 // 2

    k_sniff<<<1, 256, 0, stream>>>((const u16*)xin, (const int*)ei, flags);
    hipMemsetAsync(cnt, 0, NN * sizeof(int), stream);
    k_cvt <<<NHTOT / 4 / 256, 256, 0, stream>>>(xin, (uint2*)xc, flags);
    k_cvtw<<<(WTOT + 255) / 256, 256, 0, stream>>>(d_in[2], d_in[3], d_in[4],
            d_in[5], d_in[6], d_in[7], d_in[8], wc, flags);
    k_hist<<<(NE + 255) / 256, 256, 0, stream>>>(ei, cnt, flags);
    k_scan1<<<SCAN_B, 256, 0, stream>>>(cnt, part);
    k_scan2<<<1, 512, 0, stream>>>(part);
    k_scan3<<<SCAN_B, 256, 0, stream>>>(cnt, part, offs, cur, invdeg);
    k_sort<<<(NE + 255) / 256, 256, 0, stream>>>(ei, cur, ssrc, flags);

    const u16* Wl  = wc + OW_Wl;
    const u16* bl  = wc + OW_bl;
    const u16* Wr  = wc + OW_Wr;
    const u16* gam = wc + OW_gam;
    const u16* bet = wc + OW_bet;
    const u16* Wo  = wc + OW_Wo;
    const u16* bo  = wc + OW_bo;

    int ablk = NN * 16 / 256;        // 4 nodes/wave * 4 waves = 16 nodes/block, exact
    int gblk = (NN + 127) / 128;     // 128 nodes per block
    // layer 0: X=xc, agg->b0, gemm in place over b0
    k_agg<<<ablk, 256, 0, stream>>>((const bf16x8*)xc, offs, ssrc, invdeg, (bf16x8*)b0);
    k_gemm<0><<<gblk, 256, 0, stream>>>(xc, b0, Wl, Wr, bl, gam, bet,
                                        Wo, bo, d_out, flags);
    // layer 1: X=b0, agg->xc, gemm in place over xc (Wr has +I folded)
    k_agg<<<ablk, 256, 0, stream>>>((const bf16x8*)b0, offs, ssrc, invdeg, (bf16x8*)xc);
    k_gemm<0><<<gblk, 256, 0, stream>>>(b0, xc,
            Wl + HH * HH, Wr + HH * HH, bl + HH, gam + HH, bet + HH,
            Wo, bo, d_out, flags);
    // layer 2 + projection fused: X=xc, agg->b0, out <- proj(LN(...))
    k_agg<<<ablk, 256, 0, stream>>>((const bf16x8*)xc, offs, ssrc, invdeg, (bf16x8*)b0);
    k_gemm<1><<<gblk, 256, 0, stream>>>(xc, b0,
            Wl + 2 * HH * HH, Wr + 2 * HH * HH, bl + 2 * HH, gam + 2 * HH, bet + 2 * HH,
            Wo, bo, d_out, flags);
}